// Round 7
// baseline (1513.295 us; speedup 1.0000x reference)
//
#include <hip/hip_runtime.h>

#define NCLS 80
#define TPOINTS 17064
#define GN_EPS 1e-5f

typedef float v4f __attribute__((ext_vector_type(4)));
typedef short v8s __attribute__((ext_vector_type(8)));

__device__ __forceinline__ unsigned short f2bf(float f) {
    unsigned u = __float_as_uint(f);
    unsigned r = (u + 0x7FFFu + ((u >> 16) & 1u)) >> 16;
    return (unsigned short)r;
}
__device__ __forceinline__ float bf2f(unsigned short h) {
    return __uint_as_float(((unsigned)h) << 16);
}

struct Lv { int t_conv, t_gn, t_prep, t_h5, xo, P2W, PP, HW, W, H, lwW, loff; };
struct Tab { Lv lv[5]; };

// ---------------------------------------------------------------------------
// Implicit-GEMM conv, fused across levels. XOR-swizzled LDS (stride 32, no
// pad): element (row r, 16B-chunk c) lives at r*32 + (c ^ ((r>>1)&3))*8.
// Two-phase register prefetch over the flattened 72-step (tap,kb) K-loop.
// TOWER (HEAD=0): bf16 NHWC-padded out + fused GN stats. HEAD=1: fp32 out.
// ---------------------------------------------------------------------------
template<int HEAD>
__global__ __launch_bounds__(256) void conv_k(
    const unsigned short* __restrict__ xin,
    const unsigned short* __restrict__ wt, int wrows,
    const float* __restrict__ bias,
    unsigned short* __restrict__ yout, float* __restrict__ stats, int slot,
    float* __restrict__ out, int CO, int co_out, int relu_cnt,
    Tab tb)
{
    __shared__ unsigned short sA[128 * 32];
    __shared__ unsigned short sB[128 * 32];
    const int tid = threadIdx.x, lane = tid & 63, wave = tid >> 6;
    const int bx = blockIdx.x, n = blockIdx.z;
    int L = 0;
    while (L < 4 && bx >= tb.lv[L + 1].t_conv) ++L;
    const Lv lv = tb.lv[L];
    const int pp0 = (bx - lv.t_conv) * 128;
    const int co0 = HEAD ? 0 : blockIdx.y * 128;

    v4f acc[4][4];
#pragma unroll
    for (int i = 0; i < 4; ++i)
#pragma unroll
        for (int j = 0; j < 4; ++j) acc[i][j] = (v4f)0.f;

    // staging: thread owns logical chunks {2b, 2b+1} of row srow (32B)
    const int srow = tid >> 1, b = tid & 1;
    const int sch = b * 16;
    const int s0 = (srow >> 1) & 1, s1 = (srow >> 2) & 1;
    const int wbase = srow * 32 + ((b ^ s1) << 4);
    const int wo0 = wbase + s0 * 8;          // physical slot of logical half 0
    const int wo1 = wbase + (s0 ^ 1) * 8;    // physical slot of logical half 1
    const unsigned short* xb = xin + (size_t)lv.xo + (size_t)n * lv.PP * 256;
    const unsigned short* arow = wt + (size_t)(co0 + srow) * 256 + sch;
    const unsigned short* brow = xb + (size_t)(pp0 + srow) * 256 + sch;
    const size_t wstride = (size_t)wrows * 256;

    const int col = lane & 15, q = lane >> 4;
    const int wco = (wave & 1) * 64, wpos = (wave >> 1) * 64;
    const int qs = (q ^ ((col >> 1) & 3)) << 3;   // swizzle sel (row%16==col)
    int ard[4], brd[4];
#pragma unroll
    for (int i = 0; i < 4; ++i) {
        ard[i] = (wco  + i * 16 + col) * 32 + qs;
        brd[i] = (wpos + i * 16 + col) * 32 + qs;
    }

    auto lda = [&](int step, uint4& a0, uint4& a1, uint4& b0, uint4& b1) {
        const int t = step >> 3, kb = step & 7;
        const ptrdiff_t off = ((ptrdiff_t)(t / 3) - 1) * lv.P2W + (t % 3) - 1;
        const unsigned short* at = arow + (size_t)t * wstride + kb * 32;
        const unsigned short* bt = brow + off * 256 + kb * 32;
        a0 = *(const uint4*)at; a1 = *(const uint4*)(at + 8);
        b0 = *(const uint4*)bt; b1 = *(const uint4*)(bt + 8);
    };
    auto stage = [&](const uint4& a0, const uint4& a1,
                     const uint4& b0, const uint4& b1) {
        __syncthreads();
        *(uint4*)&sA[wo0] = a0; *(uint4*)&sA[wo1] = a1;
        *(uint4*)&sB[wo0] = b0; *(uint4*)&sB[wo1] = b1;
        __syncthreads();
        v8s af[4], bfr[4];
#pragma unroll
        for (int i = 0; i < 4; ++i) af[i]  = *(const v8s*)&sA[ard[i]];
#pragma unroll
        for (int j = 0; j < 4; ++j) bfr[j] = *(const v8s*)&sB[brd[j]];
#pragma unroll
        for (int i = 0; i < 4; ++i)
#pragma unroll
            for (int j = 0; j < 4; ++j)
                acc[i][j] = __builtin_amdgcn_mfma_f32_16x16x32_bf16(
                    af[i], bfr[j], acc[i][j], 0, 0, 0);
    };

    uint4 ra0, ra1, rb0, rb1, qa0, qa1, qb0, qb1;
    lda(0, ra0, ra1, rb0, rb1);
    for (int s2 = 0; s2 < 72; s2 += 2) {
        lda(s2 + 1, qa0, qa1, qb0, qb1);
        stage(ra0, ra1, rb0, rb1);
        if (s2 + 2 < 72) lda(s2 + 2, ra0, ra1, rb0, rb1);
        stage(qa0, qa1, qb0, qb1);
    }

    if (!HEAD) {
#pragma unroll
        for (int i = 0; i < 4; ++i) {
            const int cobase = co0 + wco + i * 16 + q * 4;
            const float4 b4 = *(const float4*)(bias + cobase);
            float s = 0.f, ss = 0.f;
#pragma unroll
            for (int j = 0; j < 4; ++j) {
                const int pp = pp0 + wpos + j * 16 + col;
                const unsigned h2 = (unsigned)pp / (unsigned)lv.P2W;
                const unsigned w2 = (unsigned)pp - h2 * lv.P2W;
                const bool in = (h2 >= 1u) & (h2 <= (unsigned)lv.H) &
                                (w2 >= 1u) & (w2 <= (unsigned)lv.W);
                float v0 = acc[i][j][0] + b4.x;
                float v1 = acc[i][j][1] + b4.y;
                float v2 = acc[i][j][2] + b4.z;
                float v3 = acc[i][j][3] + b4.w;
                if (in) {
                    ushort4 pk;
                    pk.x = f2bf(v0); pk.y = f2bf(v1);
                    pk.z = f2bf(v2); pk.w = f2bf(v3);
                    *(ushort4*)(yout + (size_t)lv.xo +
                                ((size_t)n * lv.PP + pp) * 256 + cobase) = pk;
                    s  += v0 + v1 + v2 + v3;
                    ss += v0 * v0 + v1 * v1 + v2 * v2 + v3 * v3;
                }
            }
#pragma unroll
            for (int o = 32; o > 0; o >>= 1) {
                s  += __shfl_down(s, o, 64);
                ss += __shfl_down(ss, o, 64);
            }
            if (lane == 0) {
                const int g = cobase >> 4;
                const int si = (((slot * 5 + L) * 32) + n * 16 + g) * 2;
                atomicAdd(&stats[si + 0], s);
                atomicAdd(&stats[si + 1], ss);
            }
        }
    } else {
#pragma unroll
        for (int i = 0; i < 4; ++i) {
            const int cobase = wco + i * 16 + q * 4;
            float bv[4];
#pragma unroll
            for (int k = 0; k < 4; ++k)
                bv[k] = (cobase + k < CO) ? bias[cobase + k] : 0.f;
#pragma unroll
            for (int j = 0; j < 4; ++j) {
                const int pp = pp0 + wpos + j * 16 + col;
                const unsigned h2 = (unsigned)pp / (unsigned)lv.P2W;
                const unsigned w2 = (unsigned)pp - h2 * lv.P2W;
                const bool in = (h2 >= 1u) & (h2 <= (unsigned)lv.H) &
                                (w2 >= 1u) & (w2 <= (unsigned)lv.W);
                if (in) {
                    const int p = (h2 - 1) * lv.W + (w2 - 1);
                    float* ob = out + ((size_t)n * TPOINTS + lv.loff + p) * 85 + co_out;
#pragma unroll
                    for (int k = 0; k < 4; ++k) {
                        const int co = cobase + k;
                        if (co < CO) {
                            float v = acc[i][j][k] + bv[k];
                            if (co < relu_cnt) v = fmaxf(v, 0.f);
                            ob[co] = v;
                        }
                    }
                }
            }
        }
    }
}

// ---------------------------------------------------------------------------
// Small reg-head (bbox+ctr, CO=5): 16co x 256pos MFMA tile, 1 A-frag/wave.
// wt: bf16 [9][16][256]. Same swizzled-LDS protocol.
// ---------------------------------------------------------------------------
__global__ __launch_bounds__(256) void head5_k(
    const unsigned short* __restrict__ xin,
    const unsigned short* __restrict__ wt,
    const float* __restrict__ bias, float* __restrict__ out, Tab tb)
{
    __shared__ unsigned short sA[16 * 32];
    __shared__ unsigned short sB[256 * 32];
    const int tid = threadIdx.x, lane = tid & 63, wave = tid >> 6;
    const int bx = blockIdx.x, n = blockIdx.z;
    int L = 0;
    while (L < 4 && bx >= tb.lv[L + 1].t_h5) ++L;
    const Lv lv = tb.lv[L];
    const int pp0 = (bx - lv.t_h5) * 256;

    v4f acc[4];
#pragma unroll
    for (int j = 0; j < 4; ++j) acc[j] = (v4f)0.f;

    const unsigned short* xb = xin + (size_t)lv.xo + (size_t)n * lv.PP * 256;
    const unsigned short* brow = xb + (size_t)(pp0 + tid) * 256;
    const int bs = (tid >> 1) & 3;
    int bw[4];
#pragma unroll
    for (int c = 0; c < 4; ++c) bw[c] = tid * 32 + ((c ^ bs) << 3);
    const unsigned short* arow = wt + (size_t)tid * 256;   // used when tid<16

    const int col = lane & 15, q = lane >> 4;
    const int qs = (q ^ ((col >> 1) & 3)) << 3;
    const int ard = col * 32 + qs;
    const int wb = wave * 64;
    int brd[4];
#pragma unroll
    for (int j = 0; j < 4; ++j) brd[j] = (wb + j * 16 + col) * 32 + qs;

    for (int step = 0; step < 72; ++step) {
        const int t = step >> 3, kb = step & 7;
        const ptrdiff_t off = ((ptrdiff_t)(t / 3) - 1) * lv.P2W + (t % 3) - 1;
        const unsigned short* bt = brow + off * 256 + kb * 32;
        uint4 bv[4];
#pragma unroll
        for (int c = 0; c < 4; ++c) bv[c] = *(const uint4*)(bt + c * 8);
        uint4 av[4];
        if (tid < 16) {
            const unsigned short* at = arow + (size_t)t * (16 * 256) + kb * 32;
#pragma unroll
            for (int c = 0; c < 4; ++c) av[c] = *(const uint4*)(at + c * 8);
        }
        __syncthreads();
#pragma unroll
        for (int c = 0; c < 4; ++c) *(uint4*)&sB[bw[c]] = bv[c];
        if (tid < 16) {
#pragma unroll
            for (int c = 0; c < 4; ++c) *(uint4*)&sA[bw[c]] = av[c];
        }
        __syncthreads();
        v8s af = *(const v8s*)&sA[ard];
        v8s bfr[4];
#pragma unroll
        for (int j = 0; j < 4; ++j) bfr[j] = *(const v8s*)&sB[brd[j]];
#pragma unroll
        for (int j = 0; j < 4; ++j)
            acc[j] = __builtin_amdgcn_mfma_f32_16x16x32_bf16(
                af, bfr[j], acc[j], 0, 0, 0);
    }

    float bv4[4];
#pragma unroll
    for (int k = 0; k < 4; ++k) {
        const int co = q * 4 + k;
        bv4[k] = (co < 5) ? bias[co] : 0.f;
    }
#pragma unroll
    for (int j = 0; j < 4; ++j) {
        const int pp = pp0 + wb + j * 16 + col;
        const unsigned h2 = (unsigned)pp / (unsigned)lv.P2W;
        const unsigned w2 = (unsigned)pp - h2 * lv.P2W;
        const bool in = (h2 >= 1u) & (h2 <= (unsigned)lv.H) &
                        (w2 >= 1u) & (w2 <= (unsigned)lv.W);
        if (in) {
            const int p = (h2 - 1) * lv.W + (w2 - 1);
            float* ob = out + ((size_t)n * TPOINTS + lv.loff + p) * 85 + 80;
#pragma unroll
            for (int k = 0; k < 4; ++k) {
                const int co = q * 4 + k;
                if (co < 5) {
                    float v = acc[j][k] + bv4[k];
                    if (co < 4) v = fmaxf(v, 0.f);
                    ob[co] = v;
                }
            }
        }
    }
}

// ---------------------------------------------------------------------------
// GN + affine + ReLU, in-place on padded NHWC bf16 (interior only) — r6 proven.
// ---------------------------------------------------------------------------
__global__ __launch_bounds__(256) void gn_k(
    unsigned short* __restrict__ x, const float* __restrict__ stats, int slot,
    const float* __restrict__ gamma, const float* __restrict__ beta, Tab tb)
{
    const int tid = threadIdx.x, bx = blockIdx.x, n = blockIdx.z;
    int L = 0;
    while (L < 4 && bx >= tb.lv[L + 1].t_gn) ++L;
    const Lv lv = tb.lv[L];
    const int pos = (bx - lv.t_gn) * 32 + (tid >> 3);
    if (pos >= lv.HW) return;
    const int c0 = (tid & 7) * 32;
    const int h = pos >> lv.lwW, w = pos & (lv.W - 1);
    const int pp = (h + 1) * lv.P2W + (w + 1);
    unsigned short* p = x + (size_t)lv.xo + ((size_t)n * lv.PP + pp) * 256 + c0;
    const float inv = 1.0f / (16.0f * (float)lv.HW);
    const int sb = ((slot * 5 + L) * 32 + n * 16) * 2;

    float scv[32], shv[32];
#pragma unroll
    for (int gg = 0; gg < 2; ++gg) {
        const int g = (c0 >> 4) + gg;
        const float m = stats[sb + g * 2 + 0] * inv;
        const float v = stats[sb + g * 2 + 1] * inv - m * m;
        const float rs = rsqrtf(v + GN_EPS);
#pragma unroll
        for (int k = 0; k < 16; ++k) {
            const int c = g * 16 + k;
            const float sc = rs * gamma[c];
            scv[gg * 16 + k] = sc;
            shv[gg * 16 + k] = beta[c] - m * sc;
        }
    }
#pragma unroll
    for (int u = 0; u < 4; ++u) {
        uint4 a = *(const uint4*)(p + u * 8);
        unsigned wds[4] = {a.x, a.y, a.z, a.w};
#pragma unroll
        for (int k = 0; k < 4; ++k) {
            const int e = u * 8 + k * 2;
            float lo = bf2f((unsigned short)(wds[k] & 0xffffu));
            float hi = bf2f((unsigned short)(wds[k] >> 16));
            lo = fmaxf(lo * scv[e]     + shv[e],     0.f);
            hi = fmaxf(hi * scv[e + 1] + shv[e + 1], 0.f);
            wds[k] = (unsigned)f2bf(lo) | ((unsigned)f2bf(hi) << 16);
        }
        uint4 o; o.x = wds[0]; o.y = wds[1]; o.z = wds[2]; o.w = wds[3];
        *(uint4*)(p + u * 8) = o;
    }
}

// ---------------------------------------------------------------------------
// fp32 NCHW feats -> bf16 NHWC padded interior — r6 proven.
// ---------------------------------------------------------------------------
__global__ __launch_bounds__(256) void prepx_k(
    const float* f0, const float* f1, const float* f2, const float* f3,
    const float* f4, unsigned short* __restrict__ xo, Tab tb)
{
    const float* fs[5] = {f0, f1, f2, f3, f4};
    const int tid = threadIdx.x, bx = blockIdx.x, n = blockIdx.z;
    int L = 0;
    while (L < 4 && bx >= tb.lv[L + 1].t_prep) ++L;
    const Lv lv = tb.lv[L];
    const int pos = (bx - lv.t_prep) * 64 + (tid & 63);
    const int wave = tid >> 6;
    if (pos >= lv.HW) return;
    const int h = pos >> lv.lwW, w = pos & (lv.W - 1);
    const int pp = (h + 1) * lv.P2W + (w + 1);
    const float* src = fs[L] + (size_t)n * 256 * lv.HW + pos;
    unsigned short* dst = xo + (size_t)lv.xo + ((size_t)n * lv.PP + pp) * 256;
#pragma unroll
    for (int k = 0; k < 16; ++k) {
        const int c = wave * 64 + k * 4;
        ushort4 pk;
        pk.x = f2bf(src[(size_t)(c + 0) * lv.HW]);
        pk.y = f2bf(src[(size_t)(c + 1) * lv.HW]);
        pk.z = f2bf(src[(size_t)(c + 2) * lv.HW]);
        pk.w = f2bf(src[(size_t)(c + 3) * lv.HW]);
        *(ushort4*)(dst + c) = pk;
    }
}

// ---------------------------------------------------------------------------
__global__ __launch_bounds__(256) void prepwt_k(
    const float* __restrict__ cw, const float* __restrict__ rw,
    unsigned short* __restrict__ dst)
{
    const int idx = blockIdx.x * 256 + threadIdx.x;   // 54*65536
    const int ci = idx & 255, co = (idx >> 8) & 255, r = idx >> 16;
    const int tap = r % 9, layer = (r / 9) % 3, br = r / 27;
    const float* s = br ? rw : cw;
    dst[(size_t)r * 65536 + co * 256 + ci] =
        f2bf(s[(((size_t)layer * 256 + co) * 256 + ci) * 9 + tap]);
}

__global__ __launch_bounds__(256) void prepwh_k(
    const float* __restrict__ src, unsigned short* __restrict__ dst,
    int CO, int rows, int roff)
{
    const int idx = blockIdx.x * 256 + threadIdx.x;
    if (idx >= CO * 2304) return;
    const int ci = idx & 255, rr = idx >> 8;
    const int tap = rr % 9, co = rr / 9;
    dst[((size_t)tap * rows + roff + co) * 256 + ci] =
        f2bf(src[((size_t)co * 256 + ci) * 9 + tap]);
}

// ---------------------------------------------------------------------------
extern "C" void kernel_launch(void* const* d_in, const int* in_sizes, int n_in,
                              void* d_out, int out_size, void* d_ws, size_t ws_size,
                              hipStream_t stream) {
    const float* f0 = (const float*)d_in[0];
    const float* f1 = (const float*)d_in[1];
    const float* f2 = (const float*)d_in[2];
    const float* f3 = (const float*)d_in[3];
    const float* f4 = (const float*)d_in[4];
    const float* cls_w  = (const float*)d_in[5];
    const float* cls_b  = (const float*)d_in[6];
    const float* cls_g  = (const float*)d_in[7];
    const float* cls_be = (const float*)d_in[8];
    const float* log_w  = (const float*)d_in[9];
    const float* log_b  = (const float*)d_in[10];
    const float* reg_w  = (const float*)d_in[11];
    const float* reg_b  = (const float*)d_in[12];
    const float* reg_g  = (const float*)d_in[13];
    const float* reg_be = (const float*)d_in[14];
    const float* bbox_w = (const float*)d_in[15];
    const float* bbox_b = (const float*)d_in[16];
    const float* ctr_w  = (const float*)d_in[17];
    const float* ctr_b  = (const float*)d_in[18];
    float* out = (float*)d_out;

    Tab tb;
    //            t_conv t_gn t_prep t_h5 xo       P2W  PP     HW     W    H   lwW loff
    tb.lv[0] = {   0,    0,    0,    0,   0,       130, 13260, 12800, 128, 100, 7, 0     };
    tb.lv[1] = { 104,  400,  200,  52,  6789120,    66,  3432,  3200,  64,  50, 6, 12800 };
    tb.lv[2] = { 131,  500,  250,  66,  8546304,    34,   918,   800,  32,  25, 5, 16000 };
    tb.lv[3] = { 139,  525,  263,  70,  9016320,    18,   270,   208,  16,  13, 4, 16800 };
    tb.lv[4] = { 142,  532,  267,  72,  9154560,    10,    90,    56,   8,   7, 3, 17008 };
    const int NT_CONV = 143, NT_GN = 534, NT_PREP = 268, NT_H5 = 73;
    const size_t XEL = 9200640;

    char* base = (char*)d_ws;
    size_t o = 0;
    auto take = [&](size_t bytes) {
        char* p = base + o; o += (bytes + 255) & ~(size_t)255; return p;
    };
    take(262144);
    unsigned short* PX = (unsigned short*)take(XEL * 2);
    take(262144);
    unsigned short* B1 = (unsigned short*)take(XEL * 2);
    take(262144);
    unsigned short* B2 = (unsigned short*)take(XEL * 2);
    take(262144);
    unsigned short* WT  = (unsigned short*)take((size_t)54 * 65536 * 2);
    unsigned short* WHC = (unsigned short*)take((size_t)9 * 128 * 256 * 2);
    unsigned short* WHR = (unsigned short*)take((size_t)9 * 16 * 256 * 2);
    float* ST  = (float*)take(1920 * 4);
    float* RB5 = (float*)take(32);

    hipMemsetAsync(PX, 0, XEL * 2, stream);
    hipMemsetAsync(B1, 0, XEL * 2, stream);
    hipMemsetAsync(B2, 0, XEL * 2, stream);
    hipMemsetAsync(ST, 0, 1920 * 4, stream);
    hipMemcpyAsync(RB5,     bbox_b, 4 * 4, hipMemcpyDeviceToDevice, stream);
    hipMemcpyAsync(RB5 + 4, ctr_b,  1 * 4, hipMemcpyDeviceToDevice, stream);

    prepwt_k<<<dim3(13824), dim3(256), 0, stream>>>(cls_w, reg_w, WT);
    prepwh_k<<<dim3(720), dim3(256), 0, stream>>>(log_w,  WHC, 80, 128, 0);
    prepwh_k<<<dim3(36),  dim3(256), 0, stream>>>(bbox_w, WHR, 4, 16, 0);
    prepwh_k<<<dim3(9),   dim3(256), 0, stream>>>(ctr_w,  WHR, 1, 16, 4);

    const dim3 blk(256);
    prepx_k<<<dim3(NT_PREP, 1, 2), blk, 0, stream>>>(f0, f1, f2, f3, f4, PX, tb);

    // cls tower: PX -> B1 -> B2 -> B1, head(B1)
    // reg tower: PX -> B2 -> B1 -> B2, head5(B2)
    unsigned short* seq[2][4] = {{PX, B1, B2, B1}, {PX, B2, B1, B2}};
    for (int br = 0; br < 2; ++br) {
        const unsigned short* wtb = WT + (size_t)br * 27 * 65536;
        const float* cb = br ? reg_b  : cls_b;
        const float* gg = br ? reg_g  : cls_g;
        const float* gb = br ? reg_be : cls_be;
        for (int i = 0; i < 3; ++i) {
            const int slot = br * 3 + i;
            conv_k<0><<<dim3(NT_CONV, 2, 2), blk, 0, stream>>>(
                seq[br][i], wtb + (size_t)i * 9 * 65536, 256, cb + i * 256,
                seq[br][i + 1], ST, slot, nullptr, 0, 0, 0, tb);
            gn_k<<<dim3(NT_GN, 1, 2), blk, 0, stream>>>(
                seq[br][i + 1], ST, slot, gg + i * 256, gb + i * 256, tb);
        }
        if (br == 0)
            conv_k<1><<<dim3(NT_CONV, 1, 2), blk, 0, stream>>>(
                seq[0][3], WHC, 128, log_b, nullptr, nullptr, 0,
                out, NCLS, 0, 0, tb);
        else
            head5_k<<<dim3(NT_H5, 1, 2), blk, 0, stream>>>(
                seq[1][3], WHR, RB5, out, tb);
    }
}

// Round 8
// 1178.466 us; speedup vs baseline: 1.2841x; 1.2841x over previous
//
#include <hip/hip_runtime.h>

#define NCLS 80
#define TPOINTS 17064
#define GN_EPS 1e-5f

typedef float v4f __attribute__((ext_vector_type(4)));
typedef short v8s __attribute__((ext_vector_type(8)));

__device__ __forceinline__ unsigned short f2bf(float f) {
    unsigned u = __float_as_uint(f);
    unsigned r = (u + 0x7FFFu + ((u >> 16) & 1u)) >> 16;
    return (unsigned short)r;
}
__device__ __forceinline__ float bf2f(unsigned short h) {
    return __uint_as_float(((unsigned)h) << 16);
}
__device__ __forceinline__ void gload16(const unsigned short* g, unsigned short* l) {
    __builtin_amdgcn_global_load_lds(
        (const __attribute__((address_space(1))) unsigned int*)g,
        (__attribute__((address_space(3))) unsigned int*)l, 16, 0, 0);
}

struct Lv { int t_conv, t_gn, t_prep, t_h5, xo, P2W, PP, HW, W, H, lwW, loff; };
struct Tab { Lv lv[5]; };

// ---------------------------------------------------------------------------
// Implicit-GEMM conv, fused across levels AND branches (z = br*2+n).
// Staging via global_load_lds width=16 (m97 recipe): wave-uniform LDS base
// + lane*16B; LDS plain row-major [row][32] bf16. Tile 128co x 128pos.
// TOWER (HEAD=0): bf16 NHWC-padded out + fused GN stats. HEAD=1: fp32 out.
// ---------------------------------------------------------------------------
template<int HEAD>
__global__ __launch_bounds__(256) void conv_k(
    const unsigned short* __restrict__ xin, size_t xin_brs,
    const unsigned short* __restrict__ wt, size_t wt_brs, int wrows,
    const float* __restrict__ bias_c, const float* __restrict__ bias_r,
    unsigned short* __restrict__ yout, float* __restrict__ stats, int layer,
    float* __restrict__ out, int CO, int co_out, int relu_cnt,
    Tab tb)
{
    __shared__ unsigned short sA[128 * 32];
    __shared__ unsigned short sB[128 * 32];
    const int tid = threadIdx.x, lane = tid & 63, wave = tid >> 6;
    const int bx = blockIdx.x, z = blockIdx.z;
    const int n = z & 1, br = z >> 1;
    int L = 0;
    while (L < 4 && bx >= tb.lv[L + 1].t_conv) ++L;
    const Lv lv = tb.lv[L];
    const int pp0 = (bx - lv.t_conv) * 128;
    const int co0 = HEAD ? 0 : blockIdx.y * 128;
    const size_t XELs = 9200640;

    v4f acc[4][4];
#pragma unroll
    for (int i = 0; i < 4; ++i)
#pragma unroll
        for (int j = 0; j < 4; ++j) acc[i][j] = (v4f)0.f;

    const unsigned short* wtb = wt + (size_t)br * wt_brs;
    const float* bias = br ? bias_r : bias_c;
    const unsigned short* xb = xin + (size_t)br * xin_brs +
                               (size_t)lv.xo + (size_t)n * lv.PP * 256;

    // staging: wave w covers rows [w*32, w*32+32) of each 128x32 tile,
    // two gload16 per tile (16 rows = 1KB each). lane -> (row=lane>>2, 16B
    // chunk=lane&3), matching HW's base+lane*16B LDS deposit.
    const int r0 = wave * 32;
    const int lr = lane >> 2, lc = (lane & 3) * 8;
    const unsigned short* ag = wtb + (size_t)(co0 + r0 + lr) * 256 + lc;
    const unsigned short* bg = xb + (size_t)(pp0 + r0 + lr) * 256 + lc;
    unsigned short* la0 = &sA[r0 * 32];
    unsigned short* la1 = &sA[(r0 + 16) * 32];
    unsigned short* lb0 = &sB[r0 * 32];
    unsigned short* lb1 = &sB[(r0 + 16) * 32];
    const size_t wstride = (size_t)wrows * 256;

    const int col = lane & 15, q = lane >> 4;
    const int wco = (wave & 1) * 64, wpos = (wave >> 1) * 64;
    int ard[4], brd[4];
#pragma unroll
    for (int i = 0; i < 4; ++i) {
        ard[i] = (wco  + i * 16 + col) * 32 + q * 8;
        brd[i] = (wpos + i * 16 + col) * 32 + q * 8;
    }

    for (int step = 0; step < 72; ++step) {
        const int t = step >> 3, kb = step & 7;
        const ptrdiff_t off = ((ptrdiff_t)(t / 3) - 1) * lv.P2W + (t % 3) - 1;
        const unsigned short* at = ag + (size_t)t * wstride + kb * 32;
        const unsigned short* bt = bg + off * 256 + kb * 32;
        __syncthreads();               // prev frag reads done
        gload16(at, la0);
        gload16(at + 16 * 256, la1);
        gload16(bt, lb0);
        gload16(bt + 16 * 256, lb1);
        __syncthreads();               // vmcnt drain: staged data visible
        v8s af[4], bfr[4];
#pragma unroll
        for (int i = 0; i < 4; ++i) af[i]  = *(const v8s*)&sA[ard[i]];
#pragma unroll
        for (int j = 0; j < 4; ++j) bfr[j] = *(const v8s*)&sB[brd[j]];
#pragma unroll
        for (int i = 0; i < 4; ++i)
#pragma unroll
            for (int j = 0; j < 4; ++j)
                acc[i][j] = __builtin_amdgcn_mfma_f32_16x16x32_bf16(
                    af[i], bfr[j], acc[i][j], 0, 0, 0);
    }

    if (!HEAD) {
        unsigned short* yb = yout + (size_t)br * XELs + (size_t)lv.xo +
                             (size_t)n * lv.PP * 256;
        const int slot = br * 3 + layer;
#pragma unroll
        for (int i = 0; i < 4; ++i) {
            const int cobase = co0 + wco + i * 16 + q * 4;
            const float4 b4 = *(const float4*)(bias + cobase);
            float s = 0.f, ss = 0.f;
#pragma unroll
            for (int j = 0; j < 4; ++j) {
                const int pp = pp0 + wpos + j * 16 + col;
                const unsigned h2 = (unsigned)pp / (unsigned)lv.P2W;
                const unsigned w2 = (unsigned)pp - h2 * lv.P2W;
                const bool in = (h2 >= 1u) & (h2 <= (unsigned)lv.H) &
                                (w2 >= 1u) & (w2 <= (unsigned)lv.W);
                float v0 = acc[i][j][0] + b4.x;
                float v1 = acc[i][j][1] + b4.y;
                float v2 = acc[i][j][2] + b4.z;
                float v3 = acc[i][j][3] + b4.w;
                if (in) {
                    ushort4 pk;
                    pk.x = f2bf(v0); pk.y = f2bf(v1);
                    pk.z = f2bf(v2); pk.w = f2bf(v3);
                    *(ushort4*)(yb + (size_t)pp * 256 + cobase) = pk;
                    s  += v0 + v1 + v2 + v3;
                    ss += v0 * v0 + v1 * v1 + v2 * v2 + v3 * v3;
                }
            }
#pragma unroll
            for (int o = 32; o > 0; o >>= 1) {
                s  += __shfl_down(s, o, 64);
                ss += __shfl_down(ss, o, 64);
            }
            if (lane == 0) {
                const int g = cobase >> 4;
                const int si = (((slot * 5 + L) * 32) + n * 16 + g) * 2;
                atomicAdd(&stats[si + 0], s);
                atomicAdd(&stats[si + 1], ss);
            }
        }
    } else {
#pragma unroll
        for (int i = 0; i < 4; ++i) {
            const int cobase = wco + i * 16 + q * 4;
            float bv[4];
#pragma unroll
            for (int k = 0; k < 4; ++k)
                bv[k] = (cobase + k < CO) ? bias[cobase + k] : 0.f;
#pragma unroll
            for (int j = 0; j < 4; ++j) {
                const int pp = pp0 + wpos + j * 16 + col;
                const unsigned h2 = (unsigned)pp / (unsigned)lv.P2W;
                const unsigned w2 = (unsigned)pp - h2 * lv.P2W;
                const bool in = (h2 >= 1u) & (h2 <= (unsigned)lv.H) &
                                (w2 >= 1u) & (w2 <= (unsigned)lv.W);
                if (in) {
                    const int p = (h2 - 1) * lv.W + (w2 - 1);
                    float* ob = out + ((size_t)n * TPOINTS + lv.loff + p) * 85 + co_out;
#pragma unroll
                    for (int k = 0; k < 4; ++k) {
                        const int co = cobase + k;
                        if (co < CO) {
                            float v = acc[i][j][k] + bv[k];
                            if (co < relu_cnt) v = fmaxf(v, 0.f);
                            ob[co] = v;
                        }
                    }
                }
            }
        }
    }
}

// ---------------------------------------------------------------------------
// Small reg-head (bbox+ctr, CO=5) — r7 proven. 16co x 256pos, swizzled LDS.
// ---------------------------------------------------------------------------
__global__ __launch_bounds__(256) void head5_k(
    const unsigned short* __restrict__ xin,
    const unsigned short* __restrict__ wt,
    const float* __restrict__ bias, float* __restrict__ out, Tab tb)
{
    __shared__ unsigned short sA[16 * 32];
    __shared__ unsigned short sB[256 * 32];
    const int tid = threadIdx.x, lane = tid & 63, wave = tid >> 6;
    const int bx = blockIdx.x, n = blockIdx.z;
    int L = 0;
    while (L < 4 && bx >= tb.lv[L + 1].t_h5) ++L;
    const Lv lv = tb.lv[L];
    const int pp0 = (bx - lv.t_h5) * 256;

    v4f acc[4];
#pragma unroll
    for (int j = 0; j < 4; ++j) acc[j] = (v4f)0.f;

    const unsigned short* xb = xin + (size_t)lv.xo + (size_t)n * lv.PP * 256;
    const unsigned short* brow = xb + (size_t)(pp0 + tid) * 256;
    const int bs = (tid >> 1) & 3;
    int bw[4];
#pragma unroll
    for (int c = 0; c < 4; ++c) bw[c] = tid * 32 + ((c ^ bs) << 3);
    const unsigned short* arow = wt + (size_t)tid * 256;

    const int col = lane & 15, q = lane >> 4;
    const int qs = (q ^ ((col >> 1) & 3)) << 3;
    const int ard = col * 32 + qs;
    const int wb = wave * 64;
    int brd[4];
#pragma unroll
    for (int j = 0; j < 4; ++j) brd[j] = (wb + j * 16 + col) * 32 + qs;

    for (int step = 0; step < 72; ++step) {
        const int t = step >> 3, kb = step & 7;
        const ptrdiff_t off = ((ptrdiff_t)(t / 3) - 1) * lv.P2W + (t % 3) - 1;
        const unsigned short* bt = brow + off * 256 + kb * 32;
        uint4 bv[4];
#pragma unroll
        for (int c = 0; c < 4; ++c) bv[c] = *(const uint4*)(bt + c * 8);
        uint4 av[4];
        if (tid < 16) {
            const unsigned short* at = arow + (size_t)t * (16 * 256) + kb * 32;
#pragma unroll
            for (int c = 0; c < 4; ++c) av[c] = *(const uint4*)(at + c * 8);
        }
        __syncthreads();
#pragma unroll
        for (int c = 0; c < 4; ++c) *(uint4*)&sB[bw[c]] = bv[c];
        if (tid < 16) {
#pragma unroll
            for (int c = 0; c < 4; ++c) *(uint4*)&sA[bw[c]] = av[c];
        }
        __syncthreads();
        v8s af = *(const v8s*)&sA[ard];
        v8s bfr[4];
#pragma unroll
        for (int j = 0; j < 4; ++j) bfr[j] = *(const v8s*)&sB[brd[j]];
#pragma unroll
        for (int j = 0; j < 4; ++j)
            acc[j] = __builtin_amdgcn_mfma_f32_16x16x32_bf16(
                af, bfr[j], acc[j], 0, 0, 0);
    }

    float bv4[4];
#pragma unroll
    for (int k = 0; k < 4; ++k) {
        const int co = q * 4 + k;
        bv4[k] = (co < 5) ? bias[co] : 0.f;
    }
#pragma unroll
    for (int j = 0; j < 4; ++j) {
        const int pp = pp0 + wb + j * 16 + col;
        const unsigned h2 = (unsigned)pp / (unsigned)lv.P2W;
        const unsigned w2 = (unsigned)pp - h2 * lv.P2W;
        const bool in = (h2 >= 1u) & (h2 <= (unsigned)lv.H) &
                        (w2 >= 1u) & (w2 <= (unsigned)lv.W);
        if (in) {
            const int p = (h2 - 1) * lv.W + (w2 - 1);
            float* ob = out + ((size_t)n * TPOINTS + lv.loff + p) * 85 + 80;
#pragma unroll
            for (int k = 0; k < 4; ++k) {
                const int co = q * 4 + k;
                if (co < 5) {
                    float v = acc[j][k] + bv4[k];
                    if (co < 4) v = fmaxf(v, 0.f);
                    ob[co] = v;
                }
            }
        }
    }
}

// ---------------------------------------------------------------------------
// GN + affine + ReLU, in-place, fused across levels AND branches (z=br*2+n).
// ---------------------------------------------------------------------------
__global__ __launch_bounds__(256) void gn_k(
    unsigned short* __restrict__ x, const float* __restrict__ stats, int layer,
    const float* __restrict__ g_c, const float* __restrict__ be_c,
    const float* __restrict__ g_r, const float* __restrict__ be_r, Tab tb)
{
    const int tid = threadIdx.x, bx = blockIdx.x, z = blockIdx.z;
    const int n = z & 1, br = z >> 1;
    const size_t XELs = 9200640;
    int L = 0;
    while (L < 4 && bx >= tb.lv[L + 1].t_gn) ++L;
    const Lv lv = tb.lv[L];
    const int pos = (bx - lv.t_gn) * 32 + (tid >> 3);
    if (pos >= lv.HW) return;
    const int slot = br * 3 + layer;
    const float* gamma = (br ? g_r : g_c) + layer * 256;
    const float* beta  = (br ? be_r : be_c) + layer * 256;
    const int c0 = (tid & 7) * 32;
    const int h = pos >> lv.lwW, w = pos & (lv.W - 1);
    const int pp = (h + 1) * lv.P2W + (w + 1);
    unsigned short* p = x + (size_t)br * XELs + (size_t)lv.xo +
                        ((size_t)n * lv.PP + pp) * 256 + c0;
    const float inv = 1.0f / (16.0f * (float)lv.HW);
    const int sb = ((slot * 5 + L) * 32 + n * 16) * 2;

    float scv[32], shv[32];
#pragma unroll
    for (int gg = 0; gg < 2; ++gg) {
        const int g = (c0 >> 4) + gg;
        const float m = stats[sb + g * 2 + 0] * inv;
        const float v = stats[sb + g * 2 + 1] * inv - m * m;
        const float rs = rsqrtf(v + GN_EPS);
#pragma unroll
        for (int k = 0; k < 16; ++k) {
            const int c = g * 16 + k;
            const float sc = rs * gamma[c];
            scv[gg * 16 + k] = sc;
            shv[gg * 16 + k] = beta[c] - m * sc;
        }
    }
#pragma unroll
    for (int u = 0; u < 4; ++u) {
        uint4 a = *(const uint4*)(p + u * 8);
        unsigned wds[4] = {a.x, a.y, a.z, a.w};
#pragma unroll
        for (int k = 0; k < 4; ++k) {
            const int e = u * 8 + k * 2;
            float lo = bf2f((unsigned short)(wds[k] & 0xffffu));
            float hi = bf2f((unsigned short)(wds[k] >> 16));
            lo = fmaxf(lo * scv[e]     + shv[e],     0.f);
            hi = fmaxf(hi * scv[e + 1] + shv[e + 1], 0.f);
            wds[k] = (unsigned)f2bf(lo) | ((unsigned)f2bf(hi) << 16);
        }
        uint4 o; o.x = wds[0]; o.y = wds[1]; o.z = wds[2]; o.w = wds[3];
        *(uint4*)(p + u * 8) = o;
    }
}

// ---------------------------------------------------------------------------
// fp32 NCHW feats -> bf16 NHWC padded interior — proven.
// ---------------------------------------------------------------------------
__global__ __launch_bounds__(256) void prepx_k(
    const float* f0, const float* f1, const float* f2, const float* f3,
    const float* f4, unsigned short* __restrict__ xo, Tab tb)
{
    const float* fs[5] = {f0, f1, f2, f3, f4};
    const int tid = threadIdx.x, bx = blockIdx.x, n = blockIdx.z;
    int L = 0;
    while (L < 4 && bx >= tb.lv[L + 1].t_prep) ++L;
    const Lv lv = tb.lv[L];
    const int pos = (bx - lv.t_prep) * 64 + (tid & 63);
    const int wave = tid >> 6;
    if (pos >= lv.HW) return;
    const int h = pos >> lv.lwW, w = pos & (lv.W - 1);
    const int pp = (h + 1) * lv.P2W + (w + 1);
    const float* src = fs[L] + (size_t)n * 256 * lv.HW + pos;
    unsigned short* dst = xo + (size_t)lv.xo + ((size_t)n * lv.PP + pp) * 256;
#pragma unroll
    for (int k = 0; k < 16; ++k) {
        const int c = wave * 64 + k * 4;
        ushort4 pk;
        pk.x = f2bf(src[(size_t)(c + 0) * lv.HW]);
        pk.y = f2bf(src[(size_t)(c + 1) * lv.HW]);
        pk.z = f2bf(src[(size_t)(c + 2) * lv.HW]);
        pk.w = f2bf(src[(size_t)(c + 3) * lv.HW]);
        *(ushort4*)(dst + c) = pk;
    }
}

// ---------------------------------------------------------------------------
__global__ __launch_bounds__(256) void prepwt_k(
    const float* __restrict__ cw, const float* __restrict__ rw,
    unsigned short* __restrict__ dst)
{
    const int idx = blockIdx.x * 256 + threadIdx.x;   // 54*65536
    const int ci = idx & 255, co = (idx >> 8) & 255, r = idx >> 16;
    const int tap = r % 9, layer = (r / 9) % 3, br = r / 27;
    const float* s = br ? rw : cw;
    dst[(size_t)r * 65536 + co * 256 + ci] =
        f2bf(s[(((size_t)layer * 256 + co) * 256 + ci) * 9 + tap]);
}

__global__ __launch_bounds__(256) void prepwh_k(
    const float* __restrict__ src, unsigned short* __restrict__ dst,
    int CO, int rows, int roff)
{
    const int idx = blockIdx.x * 256 + threadIdx.x;
    if (idx >= CO * 2304) return;
    const int ci = idx & 255, rr = idx >> 8;
    const int tap = rr % 9, co = rr / 9;
    dst[((size_t)tap * rows + roff + co) * 256 + ci] =
        f2bf(src[((size_t)co * 256 + ci) * 9 + tap]);
}

// ---------------------------------------------------------------------------
extern "C" void kernel_launch(void* const* d_in, const int* in_sizes, int n_in,
                              void* d_out, int out_size, void* d_ws, size_t ws_size,
                              hipStream_t stream) {
    const float* f0 = (const float*)d_in[0];
    const float* f1 = (const float*)d_in[1];
    const float* f2 = (const float*)d_in[2];
    const float* f3 = (const float*)d_in[3];
    const float* f4 = (const float*)d_in[4];
    const float* cls_w  = (const float*)d_in[5];
    const float* cls_b  = (const float*)d_in[6];
    const float* cls_g  = (const float*)d_in[7];
    const float* cls_be = (const float*)d_in[8];
    const float* log_w  = (const float*)d_in[9];
    const float* log_b  = (const float*)d_in[10];
    const float* reg_w  = (const float*)d_in[11];
    const float* reg_b  = (const float*)d_in[12];
    const float* reg_g  = (const float*)d_in[13];
    const float* reg_be = (const float*)d_in[14];
    const float* bbox_w = (const float*)d_in[15];
    const float* bbox_b = (const float*)d_in[16];
    const float* ctr_w  = (const float*)d_in[17];
    const float* ctr_b  = (const float*)d_in[18];
    float* out = (float*)d_out;

    Tab tb;
    //            t_conv t_gn t_prep t_h5 xo       P2W  PP     HW     W    H   lwW loff
    tb.lv[0] = {   0,    0,    0,    0,   0,       130, 13260, 12800, 128, 100, 7, 0     };
    tb.lv[1] = { 104,  400,  200,  52,  6789120,    66,  3432,  3200,  64,  50, 6, 12800 };
    tb.lv[2] = { 131,  500,  250,  66,  8546304,    34,   918,   800,  32,  25, 5, 16000 };
    tb.lv[3] = { 139,  525,  263,  70,  9016320,    18,   270,   208,  16,  13, 4, 16800 };
    tb.lv[4] = { 142,  532,  267,  72,  9154560,    10,    90,    56,   8,   7, 3, 17008 };
    const int NT_CONV = 143, NT_GN = 534, NT_PREP = 268, NT_H5 = 73;
    const size_t XEL = 9200640;

    char* base = (char*)d_ws;
    size_t o = 0;
    auto take = [&](size_t bytes) {
        char* p = base + o; o += (bytes + 255) & ~(size_t)255; return p;
    };
    take(131072);                                        // guard 128KB
    unsigned short* PX = (unsigned short*)take(XEL * 2);          // shared input
    take(131072);
    unsigned short* B1 = (unsigned short*)take(XEL * 2 * 2);      // [br]
    take(131072);
    unsigned short* B2 = (unsigned short*)take(XEL * 2 * 2);      // [br]
    take(131072);
    unsigned short* WT  = (unsigned short*)take((size_t)54 * 65536 * 2);
    unsigned short* WHC = (unsigned short*)take((size_t)9 * 128 * 256 * 2);
    unsigned short* WHR = (unsigned short*)take((size_t)9 * 16 * 256 * 2);
    float* ST  = (float*)take(1920 * 4);
    float* RB5 = (float*)take(32);

    hipMemsetAsync(PX, 0, XEL * 2, stream);
    hipMemsetAsync(B1, 0, XEL * 4, stream);
    hipMemsetAsync(B2, 0, XEL * 4, stream);
    hipMemsetAsync(ST, 0, 1920 * 4, stream);
    hipMemcpyAsync(RB5,     bbox_b, 4 * 4, hipMemcpyDeviceToDevice, stream);
    hipMemcpyAsync(RB5 + 4, ctr_b,  1 * 4, hipMemcpyDeviceToDevice, stream);

    prepwt_k<<<dim3(13824), dim3(256), 0, stream>>>(cls_w, reg_w, WT);
    prepwh_k<<<dim3(720), dim3(256), 0, stream>>>(log_w,  WHC, 80, 128, 0);
    prepwh_k<<<dim3(36),  dim3(256), 0, stream>>>(bbox_w, WHR, 4, 16, 0);
    prepwh_k<<<dim3(9),   dim3(256), 0, stream>>>(ctr_w,  WHR, 1, 16, 4);

    const dim3 blk(256);
    prepx_k<<<dim3(NT_PREP, 1, 2), blk, 0, stream>>>(f0, f1, f2, f3, f4, PX, tb);

    // chain: conv0 PX->B1[br], gn0 B1; conv1 B1->B2, gn1 B2; conv2 B2->B1,
    // gn2 B1; cls-head B1[0]; reg-head5 B1[1].
    const size_t WBRS = (size_t)27 * 65536;
    unsigned short* cin[3]  = {PX, B1, B2};
    size_t          cbrs[3] = {0, XEL, XEL};
    unsigned short* cout_[3] = {B1, B2, B1};
    for (int i = 0; i < 3; ++i) {
        conv_k<0><<<dim3(NT_CONV, 2, 4), blk, 0, stream>>>(
            cin[i], cbrs[i], WT + (size_t)i * 9 * 65536, WBRS, 256,
            cls_b + i * 256, reg_b + i * 256,
            cout_[i], ST, i, nullptr, 0, 0, 0, tb);
        gn_k<<<dim3(NT_GN, 1, 4), blk, 0, stream>>>(
            cout_[i], ST, i, cls_g, cls_be, reg_g, reg_be, tb);
    }
    conv_k<1><<<dim3(NT_CONV, 1, 2), blk, 0, stream>>>(
        B1, 0, WHC, 0, 128, log_b, log_b,
        nullptr, nullptr, 0, out, NCLS, 0, 0, tb);
    head5_k<<<dim3(NT_H5, 1, 2), blk, 0, stream>>>(
        B1 + XEL, WHR, RB5, out, tb);
}

// Round 9
// 1063.124 us; speedup vs baseline: 1.4234x; 1.1085x over previous
//
#include <hip/hip_runtime.h>

#define NCLS 80
#define TPOINTS 17064
#define GN_EPS 1e-5f

typedef float v4f __attribute__((ext_vector_type(4)));
typedef short v8s __attribute__((ext_vector_type(8)));

__device__ __forceinline__ unsigned short f2bf(float f) {
    unsigned u = __float_as_uint(f);
    unsigned r = (u + 0x7FFFu + ((u >> 16) & 1u)) >> 16;
    return (unsigned short)r;
}
__device__ __forceinline__ float bf2f(unsigned short h) {
    return __uint_as_float(((unsigned)h) << 16);
}
__device__ __forceinline__ void gload16(const unsigned short* g, unsigned short* l) {
    __builtin_amdgcn_global_load_lds(
        (const __attribute__((address_space(1))) unsigned int*)g,
        (__attribute__((address_space(3))) unsigned int*)l, 16, 0, 0);
}

struct Lv { int t_conv, t_gn, t_prep, t_h5, xo, P2W, PP, HW, W, H, lwW, loff; };
struct Tab { Lv lv[5]; };

// ---------------------------------------------------------------------------
// Implicit-GEMM conv, fused across levels AND branches (z = br*2+n).
// BK=64: two 32-K sub-steps per barrier pair (8 gload16 in flight per drain,
// 32 MFMA per pair, 36 pairs). XOR-swizzled deposit via per-lane global
// source chunk (l&3)^((l>>3)&3); frag reads at q^((col>>1)&3) -> 2-way bank
// alias (free, m136). Tile 128co x 128pos, 4 waves of 64x64.
// TOWER (HEAD=0): bf16 NHWC-padded out + fused GN stats. HEAD=1: fp32 out.
// ---------------------------------------------------------------------------
template<int HEAD>
__global__ __launch_bounds__(256) void conv_k(
    const unsigned short* __restrict__ xin, size_t xin_brs,
    const unsigned short* __restrict__ wt, size_t wt_brs, int wrows,
    const float* __restrict__ bias_c, const float* __restrict__ bias_r,
    unsigned short* __restrict__ yout, float* __restrict__ stats, int layer,
    float* __restrict__ out, int CO, int co_out, int relu_cnt,
    Tab tb)
{
    __shared__ unsigned short sA[2 * 128 * 32];
    __shared__ unsigned short sB[2 * 128 * 32];
    const int tid = threadIdx.x, lane = tid & 63, wave = tid >> 6;
    const int bx = blockIdx.x, z = blockIdx.z;
    const int n = z & 1, br = z >> 1;
    int L = 0;
    while (L < 4 && bx >= tb.lv[L + 1].t_conv) ++L;
    const Lv lv = tb.lv[L];
    const int pp0 = (bx - lv.t_conv) * 128;
    const int co0 = HEAD ? 0 : blockIdx.y * 128;
    const size_t XELs = 9200640;

    v4f acc[4][4];
#pragma unroll
    for (int i = 0; i < 4; ++i)
#pragma unroll
        for (int j = 0; j < 4; ++j) acc[i][j] = (v4f)0.f;

    const unsigned short* wtb = wt + (size_t)br * wt_brs;
    const float* bias = br ? bias_r : bias_c;
    const unsigned short* xb = xin + (size_t)br * xin_brs +
                               (size_t)lv.xo + (size_t)n * lv.PP * 256;

    // staging: wave w covers rows [w*32, w*32+32) of each 128x32 half-tile.
    // lane l -> deposit (row = r0 + (l>>2), physical chunk = l&3); global
    // source = logical chunk (l&3)^((l>>3)&3)  => LDS holds swizzled layout.
    const int r0 = wave * 32;
    const int lr = lane >> 2;
    const int lc = ((lane & 3) ^ ((lane >> 3) & 3)) * 8;
    const unsigned short* ag = wtb + (size_t)(co0 + r0 + lr) * 256 + lc;
    const unsigned short* bg = xb + (size_t)(pp0 + r0 + lr) * 256 + lc;
    unsigned short* la = &sA[r0 * 32];
    unsigned short* lb = &sB[r0 * 32];
    const size_t wstride = (size_t)wrows * 256;

    const int col = lane & 15, q = lane >> 4;
    const int wco = (wave & 1) * 64, wpos = (wave >> 1) * 64;
    const int qs = (q ^ ((col >> 1) & 3)) << 3;
    int ard[4], brd[4];
#pragma unroll
    for (int i = 0; i < 4; ++i) {
        ard[i] = (wco  + i * 16 + col) * 32 + qs;
        brd[i] = (wpos + i * 16 + col) * 32 + qs;
    }

    auto addrs = [&](int step, const unsigned short*& at, const unsigned short*& bt) {
        const int t = step >> 3, kb = step & 7;
        const ptrdiff_t off = ((ptrdiff_t)(t / 3) - 1) * lv.P2W + (t % 3) - 1;
        at = ag + (size_t)t * wstride + kb * 32;
        bt = bg + off * 256 + kb * 32;
    };

    for (int pair = 0; pair < 36; ++pair) {
        const unsigned short *at0, *bt0, *at1, *bt1;
        addrs(2 * pair,     at0, bt0);
        addrs(2 * pair + 1, at1, bt1);
        __syncthreads();                    // prev frag reads done
        gload16(at0,            la);
        gload16(at0 + 16 * 256, la + 16 * 32);
        gload16(bt0,            lb);
        gload16(bt0 + 16 * 256, lb + 16 * 32);
        gload16(at1,            la + 4096);
        gload16(at1 + 16 * 256, la + 4096 + 16 * 32);
        gload16(bt1,            lb + 4096);
        gload16(bt1 + 16 * 256, lb + 4096 + 16 * 32);
        __syncthreads();                    // vmcnt drain: both halves staged
#pragma unroll
        for (int h = 0; h < 2; ++h) {
            const int hb = h * 4096;
            v8s af[4], bfr[4];
#pragma unroll
            for (int i = 0; i < 4; ++i) af[i]  = *(const v8s*)&sA[hb + ard[i]];
#pragma unroll
            for (int j = 0; j < 4; ++j) bfr[j] = *(const v8s*)&sB[hb + brd[j]];
#pragma unroll
            for (int i = 0; i < 4; ++i)
#pragma unroll
                for (int j = 0; j < 4; ++j)
                    acc[i][j] = __builtin_amdgcn_mfma_f32_16x16x32_bf16(
                        af[i], bfr[j], acc[i][j], 0, 0, 0);
        }
    }

    if (!HEAD) {
        unsigned short* yb = yout + (size_t)br * XELs + (size_t)lv.xo +
                             (size_t)n * lv.PP * 256;
        const int slot = br * 3 + layer;
#pragma unroll
        for (int i = 0; i < 4; ++i) {
            const int cobase = co0 + wco + i * 16 + q * 4;
            const float4 b4 = *(const float4*)(bias + cobase);
            float s = 0.f, ss = 0.f;
#pragma unroll
            for (int j = 0; j < 4; ++j) {
                const int pp = pp0 + wpos + j * 16 + col;
                const unsigned h2 = (unsigned)pp / (unsigned)lv.P2W;
                const unsigned w2 = (unsigned)pp - h2 * lv.P2W;
                const bool in = (h2 >= 1u) & (h2 <= (unsigned)lv.H) &
                                (w2 >= 1u) & (w2 <= (unsigned)lv.W);
                float v0 = acc[i][j][0] + b4.x;
                float v1 = acc[i][j][1] + b4.y;
                float v2 = acc[i][j][2] + b4.z;
                float v3 = acc[i][j][3] + b4.w;
                if (in) {
                    ushort4 pk;
                    pk.x = f2bf(v0); pk.y = f2bf(v1);
                    pk.z = f2bf(v2); pk.w = f2bf(v3);
                    *(ushort4*)(yb + (size_t)pp * 256 + cobase) = pk;
                    s  += v0 + v1 + v2 + v3;
                    ss += v0 * v0 + v1 * v1 + v2 * v2 + v3 * v3;
                }
            }
#pragma unroll
            for (int o = 32; o > 0; o >>= 1) {
                s  += __shfl_down(s, o, 64);
                ss += __shfl_down(ss, o, 64);
            }
            if (lane == 0) {
                const int g = cobase >> 4;
                const int si = (((slot * 5 + L) * 32) + n * 16 + g) * 2;
                atomicAdd(&stats[si + 0], s);
                atomicAdd(&stats[si + 1], ss);
            }
        }
    } else {
#pragma unroll
        for (int i = 0; i < 4; ++i) {
            const int cobase = wco + i * 16 + q * 4;
            float bv[4];
#pragma unroll
            for (int k = 0; k < 4; ++k)
                bv[k] = (cobase + k < CO) ? bias[cobase + k] : 0.f;
#pragma unroll
            for (int j = 0; j < 4; ++j) {
                const int pp = pp0 + wpos + j * 16 + col;
                const unsigned h2 = (unsigned)pp / (unsigned)lv.P2W;
                const unsigned w2 = (unsigned)pp - h2 * lv.P2W;
                const bool in = (h2 >= 1u) & (h2 <= (unsigned)lv.H) &
                                (w2 >= 1u) & (w2 <= (unsigned)lv.W);
                if (in) {
                    const int p = (h2 - 1) * lv.W + (w2 - 1);
                    float* ob = out + ((size_t)n * TPOINTS + lv.loff + p) * 85 + co_out;
#pragma unroll
                    for (int k = 0; k < 4; ++k) {
                        const int co = cobase + k;
                        if (co < CO) {
                            float v = acc[i][j][k] + bv[k];
                            if (co < relu_cnt) v = fmaxf(v, 0.f);
                            ob[co] = v;
                        }
                    }
                }
            }
        }
    }
}

// ---------------------------------------------------------------------------
// Small reg-head (bbox+ctr, CO=5) — proven. 16co x 256pos, swizzled LDS.
// ---------------------------------------------------------------------------
__global__ __launch_bounds__(256) void head5_k(
    const unsigned short* __restrict__ xin,
    const unsigned short* __restrict__ wt,
    const float* __restrict__ bias, float* __restrict__ out, Tab tb)
{
    __shared__ unsigned short sA[16 * 32];
    __shared__ unsigned short sB[256 * 32];
    const int tid = threadIdx.x, lane = tid & 63, wave = tid >> 6;
    const int bx = blockIdx.x, n = blockIdx.z;
    int L = 0;
    while (L < 4 && bx >= tb.lv[L + 1].t_h5) ++L;
    const Lv lv = tb.lv[L];
    const int pp0 = (bx - lv.t_h5) * 256;

    v4f acc[4];
#pragma unroll
    for (int j = 0; j < 4; ++j) acc[j] = (v4f)0.f;

    const unsigned short* xb = xin + (size_t)lv.xo + (size_t)n * lv.PP * 256;
    const unsigned short* brow = xb + (size_t)(pp0 + tid) * 256;
    const int bs = (tid >> 1) & 3;
    int bw[4];
#pragma unroll
    for (int c = 0; c < 4; ++c) bw[c] = tid * 32 + ((c ^ bs) << 3);
    const unsigned short* arow = wt + (size_t)tid * 256;

    const int col = lane & 15, q = lane >> 4;
    const int qs = (q ^ ((col >> 1) & 3)) << 3;
    const int ard = col * 32 + qs;
    const int wb = wave * 64;
    int brd[4];
#pragma unroll
    for (int j = 0; j < 4; ++j) brd[j] = (wb + j * 16 + col) * 32 + qs;

    for (int step = 0; step < 72; ++step) {
        const int t = step >> 3, kb = step & 7;
        const ptrdiff_t off = ((ptrdiff_t)(t / 3) - 1) * lv.P2W + (t % 3) - 1;
        const unsigned short* bt = brow + off * 256 + kb * 32;
        uint4 bv[4];
#pragma unroll
        for (int c = 0; c < 4; ++c) bv[c] = *(const uint4*)(bt + c * 8);
        uint4 av[4];
        if (tid < 16) {
            const unsigned short* at = arow + (size_t)t * (16 * 256) + kb * 32;
#pragma unroll
            for (int c = 0; c < 4; ++c) av[c] = *(const uint4*)(at + c * 8);
        }
        __syncthreads();
#pragma unroll
        for (int c = 0; c < 4; ++c) *(uint4*)&sB[bw[c]] = bv[c];
        if (tid < 16) {
#pragma unroll
            for (int c = 0; c < 4; ++c) *(uint4*)&sA[bw[c]] = av[c];
        }
        __syncthreads();
        v8s af = *(const v8s*)&sA[ard];
        v8s bfr[4];
#pragma unroll
        for (int j = 0; j < 4; ++j) bfr[j] = *(const v8s*)&sB[brd[j]];
#pragma unroll
        for (int j = 0; j < 4; ++j)
            acc[j] = __builtin_amdgcn_mfma_f32_16x16x32_bf16(
                af, bfr[j], acc[j], 0, 0, 0);
    }

    float bv4[4];
#pragma unroll
    for (int k = 0; k < 4; ++k) {
        const int co = q * 4 + k;
        bv4[k] = (co < 5) ? bias[co] : 0.f;
    }
#pragma unroll
    for (int j = 0; j < 4; ++j) {
        const int pp = pp0 + wb + j * 16 + col;
        const unsigned h2 = (unsigned)pp / (unsigned)lv.P2W;
        const unsigned w2 = (unsigned)pp - h2 * lv.P2W;
        const bool in = (h2 >= 1u) & (h2 <= (unsigned)lv.H) &
                        (w2 >= 1u) & (w2 <= (unsigned)lv.W);
        if (in) {
            const int p = (h2 - 1) * lv.W + (w2 - 1);
            float* ob = out + ((size_t)n * TPOINTS + lv.loff + p) * 85 + 80;
#pragma unroll
            for (int k = 0; k < 4; ++k) {
                const int co = q * 4 + k;
                if (co < 5) {
                    float v = acc[j][k] + bv4[k];
                    if (co < 4) v = fmaxf(v, 0.f);
                    ob[co] = v;
                }
            }
        }
    }
}

// ---------------------------------------------------------------------------
// GN + affine + ReLU, in-place, fused across levels AND branches (z=br*2+n).
// ---------------------------------------------------------------------------
__global__ __launch_bounds__(256) void gn_k(
    unsigned short* __restrict__ x, const float* __restrict__ stats, int layer,
    const float* __restrict__ g_c, const float* __restrict__ be_c,
    const float* __restrict__ g_r, const float* __restrict__ be_r, Tab tb)
{
    const int tid = threadIdx.x, bx = blockIdx.x, z = blockIdx.z;
    const int n = z & 1, br = z >> 1;
    const size_t XELs = 9200640;
    int L = 0;
    while (L < 4 && bx >= tb.lv[L + 1].t_gn) ++L;
    const Lv lv = tb.lv[L];
    const int pos = (bx - lv.t_gn) * 32 + (tid >> 3);
    if (pos >= lv.HW) return;
    const int slot = br * 3 + layer;
    const float* gamma = (br ? g_r : g_c) + layer * 256;
    const float* beta  = (br ? be_r : be_c) + layer * 256;
    const int c0 = (tid & 7) * 32;
    const int h = pos >> lv.lwW, w = pos & (lv.W - 1);
    const int pp = (h + 1) * lv.P2W + (w + 1);
    unsigned short* p = x + (size_t)br * XELs + (size_t)lv.xo +
                        ((size_t)n * lv.PP + pp) * 256 + c0;
    const float inv = 1.0f / (16.0f * (float)lv.HW);
    const int sb = ((slot * 5 + L) * 32 + n * 16) * 2;

    float scv[32], shv[32];
#pragma unroll
    for (int gg = 0; gg < 2; ++gg) {
        const int g = (c0 >> 4) + gg;
        const float m = stats[sb + g * 2 + 0] * inv;
        const float v = stats[sb + g * 2 + 1] * inv - m * m;
        const float rs = rsqrtf(v + GN_EPS);
#pragma unroll
        for (int k = 0; k < 16; ++k) {
            const int c = g * 16 + k;
            const float sc = rs * gamma[c];
            scv[gg * 16 + k] = sc;
            shv[gg * 16 + k] = beta[c] - m * sc;
        }
    }
#pragma unroll
    for (int u = 0; u < 4; ++u) {
        uint4 a = *(const uint4*)(p + u * 8);
        unsigned wds[4] = {a.x, a.y, a.z, a.w};
#pragma unroll
        for (int k = 0; k < 4; ++k) {
            const int e = u * 8 + k * 2;
            float lo = bf2f((unsigned short)(wds[k] & 0xffffu));
            float hi = bf2f((unsigned short)(wds[k] >> 16));
            lo = fmaxf(lo * scv[e]     + shv[e],     0.f);
            hi = fmaxf(hi * scv[e + 1] + shv[e + 1], 0.f);
            wds[k] = (unsigned)f2bf(lo) | ((unsigned)f2bf(hi) << 16);
        }
        uint4 o; o.x = wds[0]; o.y = wds[1]; o.z = wds[2]; o.w = wds[3];
        *(uint4*)(p + u * 8) = o;
    }
}

// ---------------------------------------------------------------------------
// fp32 NCHW feats -> bf16 NHWC padded interior — proven.
// ---------------------------------------------------------------------------
__global__ __launch_bounds__(256) void prepx_k(
    const float* f0, const float* f1, const float* f2, const float* f3,
    const float* f4, unsigned short* __restrict__ xo, Tab tb)
{
    const float* fs[5] = {f0, f1, f2, f3, f4};
    const int tid = threadIdx.x, bx = blockIdx.x, n = blockIdx.z;
    int L = 0;
    while (L < 4 && bx >= tb.lv[L + 1].t_prep) ++L;
    const Lv lv = tb.lv[L];
    const int pos = (bx - lv.t_prep) * 64 + (tid & 63);
    const int wave = tid >> 6;
    if (pos >= lv.HW) return;
    const int h = pos >> lv.lwW, w = pos & (lv.W - 1);
    const int pp = (h + 1) * lv.P2W + (w + 1);
    const float* src = fs[L] + (size_t)n * 256 * lv.HW + pos;
    unsigned short* dst = xo + (size_t)lv.xo + ((size_t)n * lv.PP + pp) * 256;
#pragma unroll
    for (int k = 0; k < 16; ++k) {
        const int c = wave * 64 + k * 4;
        ushort4 pk;
        pk.x = f2bf(src[(size_t)(c + 0) * lv.HW]);
        pk.y = f2bf(src[(size_t)(c + 1) * lv.HW]);
        pk.z = f2bf(src[(size_t)(c + 2) * lv.HW]);
        pk.w = f2bf(src[(size_t)(c + 3) * lv.HW]);
        *(ushort4*)(dst + c) = pk;
    }
}

// ---------------------------------------------------------------------------
__global__ __launch_bounds__(256) void prepwt_k(
    const float* __restrict__ cw, const float* __restrict__ rw,
    unsigned short* __restrict__ dst)
{
    const int idx = blockIdx.x * 256 + threadIdx.x;   // 54*65536
    const int ci = idx & 255, co = (idx >> 8) & 255, r = idx >> 16;
    const int tap = r % 9, layer = (r / 9) % 3, br = r / 27;
    const float* s = br ? rw : cw;
    dst[(size_t)r * 65536 + co * 256 + ci] =
        f2bf(s[(((size_t)layer * 256 + co) * 256 + ci) * 9 + tap]);
}

__global__ __launch_bounds__(256) void prepwh_k(
    const float* __restrict__ src, unsigned short* __restrict__ dst,
    int CO, int rows, int roff)
{
    const int idx = blockIdx.x * 256 + threadIdx.x;
    if (idx >= CO * 2304) return;
    const int ci = idx & 255, rr = idx >> 8;
    const int tap = rr % 9, co = rr / 9;
    dst[((size_t)tap * rows + roff + co) * 256 + ci] =
        f2bf(src[((size_t)co * 256 + ci) * 9 + tap]);
}

// ---------------------------------------------------------------------------
extern "C" void kernel_launch(void* const* d_in, const int* in_sizes, int n_in,
                              void* d_out, int out_size, void* d_ws, size_t ws_size,
                              hipStream_t stream) {
    const float* f0 = (const float*)d_in[0];
    const float* f1 = (const float*)d_in[1];
    const float* f2 = (const float*)d_in[2];
    const float* f3 = (const float*)d_in[3];
    const float* f4 = (const float*)d_in[4];
    const float* cls_w  = (const float*)d_in[5];
    const float* cls_b  = (const float*)d_in[6];
    const float* cls_g  = (const float*)d_in[7];
    const float* cls_be = (const float*)d_in[8];
    const float* log_w  = (const float*)d_in[9];
    const float* log_b  = (const float*)d_in[10];
    const float* reg_w  = (const float*)d_in[11];
    const float* reg_b  = (const float*)d_in[12];
    const float* reg_g  = (const float*)d_in[13];
    const float* reg_be = (const float*)d_in[14];
    const float* bbox_w = (const float*)d_in[15];
    const float* bbox_b = (const float*)d_in[16];
    const float* ctr_w  = (const float*)d_in[17];
    const float* ctr_b  = (const float*)d_in[18];
    float* out = (float*)d_out;

    Tab tb;
    //            t_conv t_gn t_prep t_h5 xo       P2W  PP     HW     W    H   lwW loff
    tb.lv[0] = {   0,    0,    0,    0,   0,       130, 13260, 12800, 128, 100, 7, 0     };
    tb.lv[1] = { 104,  400,  200,  52,  6789120,    66,  3432,  3200,  64,  50, 6, 12800 };
    tb.lv[2] = { 131,  500,  250,  66,  8546304,    34,   918,   800,  32,  25, 5, 16000 };
    tb.lv[3] = { 139,  525,  263,  70,  9016320,    18,   270,   208,  16,  13, 4, 16800 };
    tb.lv[4] = { 142,  532,  267,  72,  9154560,    10,    90,    56,   8,   7, 3, 17008 };
    const int NT_CONV = 143, NT_GN = 534, NT_PREP = 268, NT_H5 = 73;
    const size_t XEL = 9200640;

    char* base = (char*)d_ws;
    size_t o = 0;
    auto take = [&](size_t bytes) {
        char* p = base + o; o += (bytes + 255) & ~(size_t)255; return p;
    };
    take(131072);                                        // guard 128KB
    unsigned short* PX = (unsigned short*)take(XEL * 2);          // shared input
    take(131072);
    unsigned short* B1 = (unsigned short*)take(XEL * 2 * 2);      // [br]
    take(131072);
    unsigned short* B2 = (unsigned short*)take(XEL * 2 * 2);      // [br]
    take(131072);
    unsigned short* WT  = (unsigned short*)take((size_t)54 * 65536 * 2);
    unsigned short* WHC = (unsigned short*)take((size_t)9 * 128 * 256 * 2);
    unsigned short* WHR = (unsigned short*)take((size_t)9 * 16 * 256 * 2);
    float* ST  = (float*)take(1920 * 4);
    float* RB5 = (float*)take(32);

    hipMemsetAsync(PX, 0, XEL * 2, stream);
    hipMemsetAsync(B1, 0, XEL * 4, stream);
    hipMemsetAsync(B2, 0, XEL * 4, stream);
    hipMemsetAsync(ST, 0, 1920 * 4, stream);
    hipMemcpyAsync(RB5,     bbox_b, 4 * 4, hipMemcpyDeviceToDevice, stream);
    hipMemcpyAsync(RB5 + 4, ctr_b,  1 * 4, hipMemcpyDeviceToDevice, stream);

    prepwt_k<<<dim3(13824), dim3(256), 0, stream>>>(cls_w, reg_w, WT);
    prepwh_k<<<dim3(720), dim3(256), 0, stream>>>(log_w,  WHC, 80, 128, 0);
    prepwh_k<<<dim3(36),  dim3(256), 0, stream>>>(bbox_w, WHR, 4, 16, 0);
    prepwh_k<<<dim3(9),   dim3(256), 0, stream>>>(ctr_w,  WHR, 1, 16, 4);

    const dim3 blk(256);
    prepx_k<<<dim3(NT_PREP, 1, 2), blk, 0, stream>>>(f0, f1, f2, f3, f4, PX, tb);

    // chain: conv0 PX->B1[br], gn0 B1; conv1 B1->B2, gn1 B2; conv2 B2->B1,
    // gn2 B1; cls-head B1[0]; reg-head5 B1[1].
    const size_t WBRS = (size_t)27 * 65536;
    unsigned short* cin[3]  = {PX, B1, B2};
    size_t          cbrs[3] = {0, XEL, XEL};
    unsigned short* cout_[3] = {B1, B2, B1};
    for (int i = 0; i < 3; ++i) {
        conv_k<0><<<dim3(NT_CONV, 2, 4), blk, 0, stream>>>(
            cin[i], cbrs[i], WT + (size_t)i * 9 * 65536, WBRS, 256,
            cls_b + i * 256, reg_b + i * 256,
            cout_[i], ST, i, nullptr, 0, 0, 0, tb);
        gn_k<<<dim3(NT_GN, 1, 4), blk, 0, stream>>>(
            cout_[i], ST, i, cls_g, cls_be, reg_g, reg_be, tb);
    }
    conv_k<1><<<dim3(NT_CONV, 1, 2), blk, 0, stream>>>(
        B1, 0, WHC, 0, 128, log_b, log_b,
        nullptr, nullptr, 0, out, NCLS, 0, 0, tb);
    head5_k<<<dim3(NT_H5, 1, 2), blk, 0, stream>>>(
        B1 + XEL, WHR, RB5, out, tb);
}